// Round 6
// baseline (391.443 us; speedup 1.0000x reference)
//
#include <hip/hip_runtime.h>

typedef short short8 __attribute__((ext_vector_type(8)));
typedef float f32x4 __attribute__((ext_vector_type(4)));
typedef unsigned int uint2v __attribute__((ext_vector_type(2)));

__device__ __forceinline__ unsigned short f2bf(float x) {
  union { float f; unsigned int u; } v; v.f = x;
  unsigned int r = (v.u + 0x7FFFu + ((v.u >> 16) & 1u)) >> 16;
  return (unsigned short)r;
}
__device__ __forceinline__ float bf2f(unsigned short u) {
  union { unsigned int u; float f; } v; v.u = ((unsigned int)u) << 16;
  return v.f;
}

// ---------------- K0: convert weights to bf16 ----------------
__global__ __launch_bounds__(256) void k0_wconv(const float* __restrict__ qkvw,
                                                const float* __restrict__ projw,
                                                unsigned short* __restrict__ wqkvbf,
                                                unsigned short* __restrict__ wprojbf) {
  int i = blockIdx.x * 256 + threadIdx.x;
  if (i < 768 * 256) wqkvbf[i] = f2bf(qkvw[i]);
  if (i < 256 * 256) wprojbf[i] = f2bf(projw[i]);
}

// ---------------- K1: 4x4 avg pool -> wfbf (b, pos, c) bf16 ----------------
__global__ __launch_bounds__(256) void k1_pool(const float* __restrict__ x,
                                               unsigned short* __restrict__ wfbf) {
  int t = threadIdx.x;
  int blk = blockIdx.x;
  int b = blk >> 10, pos = blk & 1023;
  int y = pos >> 5, xw = pos & 31;
  const float* xb = x + (size_t)b * 4194304;
  float acc = 0.f;
  #pragma unroll
  for (int p = 0; p < 16; ++p) {
    int h = 4 * y + (p >> 2), w = 4 * xw + (p & 3);
    acc += xb[(size_t)(h * 128 + w) * 256 + t];
  }
  wfbf[(size_t)blk * 256 + t] = f2bf(acc * 0.0625f);
}

// ---------------- K2: per-window affinity (MFMA) + aggregate (registers) ----------------
__global__ __launch_bounds__(256) void k2_winaff(const float* __restrict__ x,
                                                 const unsigned short* __restrict__ wfbf,
                                                 float* __restrict__ aff2,
                                                 unsigned short* __restrict__ agg,
                                                 float* __restrict__ asum_w) {
  __shared__ float aff_lds[4][16][16];
  int tid = threadIdx.x, wv = tid >> 6, lane = tid & 63;
  int l15 = lane & 15, g = lane >> 4;
  int u = blockIdx.x * 4 + wv;          // window id
  int b = u >> 10, pos = u & 1023;
  int y = pos >> 5, xw = pos & 31;
  const float* xb = x + (size_t)b * 4194304;

  int dyi = l15 / 3 - 1, dxi = (l15 % 3) - 1;
  bool valid_n = (l15 < 9) && ((unsigned)(y + dyi) < 32u) && ((unsigned)(xw + dxi) < 32u);
  int un = valid_n ? (b * 1024 + (y + dyi) * 32 + (xw + dxi)) : 0;
  const unsigned short* wrow = wfbf + (size_t)un * 256;

  int ph = 4 * y + (l15 >> 2), pw = 4 * xw + (l15 & 3);
  const float* prow = xb + (size_t)(ph * 128 + pw) * 256;

  const short8 zero8 = {0, 0, 0, 0, 0, 0, 0, 0};
  f32x4 S = {0.f, 0.f, 0.f, 0.f};
  #pragma unroll
  for (int cc = 0; cc < 256; cc += 32) {
    short8 af = *(const short8*)(wrow + cc + g * 8);
    af = valid_n ? af : zero8;
    f32x4 lo = *(const f32x4*)(prow + cc + g * 8);
    f32x4 hi = *(const f32x4*)(prow + cc + g * 8 + 4);
    union { unsigned int w[4]; f32x4 f; } L, H;
    L.f = lo; H.f = hi;
    union { unsigned int w[4]; short8 s; } cv;
    cv.w[0] = (L.w[1] & 0xFFFF0000u) | (L.w[0] >> 16);
    cv.w[1] = (L.w[3] & 0xFFFF0000u) | (L.w[2] >> 16);
    cv.w[2] = (H.w[1] & 0xFFFF0000u) | (H.w[0] >> 16);
    cv.w[3] = (H.w[3] & 0xFFFF0000u) | (H.w[2] >> 16);
    S = __builtin_amdgcn_mfma_f32_16x16x32_bf16(af, cv.s, S, 0, 0, 0);
  }

  const float scale = 0.0625f;
  float Lg[4], e4[4];
  float pmax = -1e30f;
  #pragma unroll
  for (int r = 0; r < 4; ++r) {
    Lg[r] = S[r] * scale;
    bool v = (g * 4 + r) < 9;
    pmax = v ? fmaxf(pmax, Lg[r]) : pmax;
  }
  pmax = fmaxf(pmax, __shfl_xor(pmax, 16));
  pmax = fmaxf(pmax, __shfl_xor(pmax, 32));
  float esum = 0.f;
  #pragma unroll
  for (int r = 0; r < 4; ++r) {
    bool v = (g * 4 + r) < 9;
    e4[r] = v ? __expf(Lg[r] - pmax) : 0.f;
    esum += e4[r];
  }
  esum += __shfl_xor(esum, 16);
  esum += __shfl_xor(esum, 32);
  float inv = 1.f / esum;
  int rowbase = (b * 32 + y) * 4752;
  #pragma unroll
  for (int r = 0; r < 4; ++r) {
    float a = e4[r] * inv;
    aff_lds[wv][g * 4 + r][l15] = a;
    float s = a;
    s += __shfl_xor(s, 1); s += __shfl_xor(s, 2);
    s += __shfl_xor(s, 4); s += __shfl_xor(s, 8);
    if ((g * 4 + r) < 9) {
      aff2[rowbase + (l15 * 9 + g * 4 + r) * 33 + xw] = a;
      if (l15 == 0) asum_w[u * 9 + g * 4 + r] = s;
    }
  }

  f32x4 acc[9] = {};
  #pragma unroll
  for (int p = 0; p < 16; ++p) {
    int phh = 4 * y + (p >> 2), pww = 4 * xw + (p & 3);
    f32x4 pf = *(const f32x4*)(xb + (size_t)(phh * 128 + pww) * 256 + 4 * lane);
    #pragma unroll
    for (int k = 0; k < 9; ++k) {
      float ab = aff_lds[wv][k][p];
      acc[k] += ab * pf;
    }
  }
  #pragma unroll
  for (int k = 0; k < 9; ++k) {
    uint2v st;
    st.x = ((unsigned int)f2bf(acc[k][1]) << 16) | f2bf(acc[k][0]);
    st.y = ((unsigned int)f2bf(acc[k][3]) << 16) | f2bf(acc[k][2]);
    *(uint2v*)(agg + ((size_t)u * 9 + k) * 256 + 4 * lane) = st;
  }
}

// ---------------- K3: gather fold + normalize -> wf2 bf16 (b, pos, c) ----------------
__global__ __launch_bounds__(256) void k3_gather(const unsigned short* __restrict__ agg,
                                                 const float* __restrict__ asum_w,
                                                 unsigned short* __restrict__ wf2bf) {
  int t = threadIdx.x;
  int blk = blockIdx.x;
  int b = blk >> 10, pos = blk & 1023;
  int y = pos >> 5, xw = pos & 31;
  float acc = 0.f, den = 0.f;
  #pragma unroll
  for (int i = 0; i < 9; ++i) {
    int dy = i / 3 - 1, dx = i % 3 - 1;
    int sy = y - dy, sx = xw - dx;
    if (sy < 0 || sy >= 32 || sx < 0 || sx >= 32) continue;
    size_t un = (size_t)(b * 1024) + sy * 32 + sx;
    acc += bf2f(agg[(un * 9 + i) * 256 + t]);
    den += asum_w[un * 9 + i];
  }
  wf2bf[(size_t)blk * 256 + t] = f2bf(acc / (den + 1e-12f));
}

// ---------------- K4: qkv GEMM (768x256 @ 256x1024 per b), MFMA bf16 ----------------
__global__ __launch_bounds__(256) void k4_qkv(const unsigned short* __restrict__ wbf,
                                              const unsigned short* __restrict__ xbf,
                                              unsigned short* __restrict__ qt,
                                              unsigned short* __restrict__ kt,
                                              unsigned short* __restrict__ vt) {
  int tid = threadIdx.x, lane = tid & 63, wv = tid >> 6;
  int l15 = lane & 15, g = lane >> 4;
  int nb = blockIdx.x * 64 + (wv & 1) * 32;
  int ob = blockIdx.y * 64 + (wv >> 1) * 32;
  int b = blockIdx.z;
  const unsigned short* X = xbf + (size_t)b * 262144;
  f32x4 acc[2][2] = {};
  for (int cc = 0; cc < 256; cc += 32) {
    short8 af[2], bfr[2];
    #pragma unroll
    for (int oi = 0; oi < 2; ++oi)
      af[oi] = *(const short8*)(wbf + (size_t)(ob + oi * 16 + l15) * 256 + cc + g * 8);
    #pragma unroll
    for (int ni = 0; ni < 2; ++ni)
      bfr[ni] = *(const short8*)(X + (size_t)(nb + ni * 16 + l15) * 256 + cc + g * 8);
    #pragma unroll
    for (int oi = 0; oi < 2; ++oi)
      #pragma unroll
      for (int ni = 0; ni < 2; ++ni)
        acc[oi][ni] = __builtin_amdgcn_mfma_f32_16x16x32_bf16(af[oi], bfr[ni], acc[oi][ni], 0, 0, 0);
  }
  #pragma unroll
  for (int oi = 0; oi < 2; ++oi)
    #pragma unroll
    for (int ni = 0; ni < 2; ++ni)
      #pragma unroll
      for (int r = 0; r < 4; ++r) {
        int o = ob + oi * 16 + g * 4 + r;
        int n = nb + ni * 16 + l15;
        unsigned short bv = f2bf(acc[oi][ni][r]);
        int head = o / 96;
        int rr = o - head * 96;
        size_t bh = (size_t)(b * 8 + head);
        if (rr < 32) qt[(bh * 1024 + n) * 32 + rr] = bv;
        else if (rr < 64) kt[(bh * 1024 + n) * 32 + (rr - 32)] = bv;
        else vt[(bh * 32 + (rr - 64)) * 1024 + n] = bv;
      }
}

// ---------------- K5: attention per (b,h,mtile), softmax over keys ----------------
__global__ __launch_bounds__(256) void k5_attn(const unsigned short* __restrict__ qt,
                                               const unsigned short* __restrict__ kt,
                                               const unsigned short* __restrict__ vt,
                                               unsigned short* __restrict__ refpre) {
  __shared__ short P_lds[4][32][40];
  __shared__ float out_lds[4][32][33];
  __shared__ float den_lds[4][32];
  int tid = threadIdx.x, lane = tid & 63, wv = tid >> 6;
  int l15 = lane & 15, g = lane >> 4;
  int mt = blockIdx.x, h = blockIdx.y, b = blockIdx.z;
  const unsigned short* qtb = qt + ((size_t)(b * 8 + h) * 1024) * 32;
  const unsigned short* ktb = kt + ((size_t)(b * 8 + h) * 1024) * 32;
  const unsigned short* vtb = vt + ((size_t)(b * 8 + h) * 32) * 1024;

  short8 qf[2];
  #pragma unroll
  for (int mi = 0; mi < 2; ++mi) {
    int m = mt * 32 + mi * 16 + l15;
    qf[mi] = *(const short8*)(qtb + (size_t)m * 32 + g * 8);
  }
  f32x4 oacc[2][2] = {};
  float dsum0 = 0.f, dsum1 = 0.f;
  const float hs = 0.17677669529663687f;

  for (int c8 = 0; c8 < 8; ++c8) {
    int nchunk = wv * 256 + c8 * 32;
    f32x4 sf[2][2];
    #pragma unroll
    for (int nt = 0; nt < 2; ++nt) {
      int n = nchunk + nt * 16 + l15;
      short8 kf = *(const short8*)(ktb + (size_t)n * 32 + g * 8);
      #pragma unroll
      for (int mi = 0; mi < 2; ++mi) {
        f32x4 z = {0.f, 0.f, 0.f, 0.f};
        sf[nt][mi] = __builtin_amdgcn_mfma_f32_16x16x32_bf16(kf, qf[mi], z, 0, 0, 0);
      }
    }
    #pragma unroll
    for (int nt = 0; nt < 2; ++nt)
      #pragma unroll
      for (int mi = 0; mi < 2; ++mi) {
        float p0 = __expf(hs * sf[nt][mi][0]);
        float p1 = __expf(hs * sf[nt][mi][1]);
        float p2 = __expf(hs * sf[nt][mi][2]);
        float p3 = __expf(hs * sf[nt][mi][3]);
        float ds = (p0 + p1) + (p2 + p3);
        if (mi == 0) dsum0 += ds; else dsum1 += ds;
        unsigned int w01 = ((unsigned int)f2bf(p1) << 16) | f2bf(p0);
        unsigned int w23 = ((unsigned int)f2bf(p3) << 16) | f2bf(p2);
        int ml = mi * 16 + l15;
        int nn = nt * 16 + g * 4;
        *(unsigned int*)&P_lds[wv][ml][nn] = w01;
        *(unsigned int*)&P_lds[wv][ml][nn + 2] = w23;
      }
    #pragma unroll
    for (int dh = 0; dh < 2; ++dh) {
      short8 vf = *(const short8*)(vtb + (size_t)(dh * 16 + l15) * 1024 + nchunk + g * 8);
      #pragma unroll
      for (int mi = 0; mi < 2; ++mi) {
        short8 pf = *(const short8*)&P_lds[wv][mi * 16 + l15][g * 8];
        oacc[dh][mi] = __builtin_amdgcn_mfma_f32_16x16x32_bf16(vf, pf, oacc[dh][mi], 0, 0, 0);
      }
    }
  }

  dsum0 += __shfl_xor(dsum0, 16); dsum0 += __shfl_xor(dsum0, 32);
  dsum1 += __shfl_xor(dsum1, 16); dsum1 += __shfl_xor(dsum1, 32);
  if (lane < 16) { den_lds[wv][lane] = dsum0; den_lds[wv][16 + lane] = dsum1; }
  #pragma unroll
  for (int dh = 0; dh < 2; ++dh)
    #pragma unroll
    for (int mi = 0; mi < 2; ++mi)
      #pragma unroll
      for (int r = 0; r < 4; ++r)
        out_lds[wv][dh * 16 + g * 4 + r][mi * 16 + l15] = oacc[dh][mi][r];
  __syncthreads();

  #pragma unroll
  for (int kk = 0; kk < 4; ++kk) {
    int idx = kk * 256 + tid;
    int d = idx & 31, m = idx >> 5;
    float v = out_lds[0][d][m] + out_lds[1][d][m] + out_lds[2][d][m] + out_lds[3][d][m];
    float den = den_lds[0][m] + den_lds[1][m] + den_lds[2][m] + den_lds[3][m];
    float res = v / den;
    int n = mt * 32 + m;
    refpre[((size_t)(b * 1024) + n) * 256 + h * 32 + d] = f2bf(res);
  }
}

// ---------------- K6: proj GEMM + bias -> reft (b, pos, c) f32 ----------------
__global__ __launch_bounds__(256) void k6_proj(const unsigned short* __restrict__ wbf,
                                               const unsigned short* __restrict__ xbf,
                                               const float* __restrict__ bias,
                                               float* __restrict__ reft) {
  int tid = threadIdx.x, lane = tid & 63, wv = tid >> 6;
  int l15 = lane & 15, g = lane >> 4;
  int nb = blockIdx.x * 64 + (wv & 1) * 32;
  int ob = blockIdx.y * 64 + (wv >> 1) * 32;
  int b = blockIdx.z;
  const unsigned short* X = xbf + (size_t)b * 262144;
  f32x4 acc[2][2] = {};
  for (int cc = 0; cc < 256; cc += 32) {
    short8 af[2], bfr[2];
    #pragma unroll
    for (int oi = 0; oi < 2; ++oi)
      af[oi] = *(const short8*)(wbf + (size_t)(ob + oi * 16 + l15) * 256 + cc + g * 8);
    #pragma unroll
    for (int ni = 0; ni < 2; ++ni)
      bfr[ni] = *(const short8*)(X + (size_t)(nb + ni * 16 + l15) * 256 + cc + g * 8);
    #pragma unroll
    for (int oi = 0; oi < 2; ++oi)
      #pragma unroll
      for (int ni = 0; ni < 2; ++ni)
        acc[oi][ni] = __builtin_amdgcn_mfma_f32_16x16x32_bf16(af[oi], bfr[ni], acc[oi][ni], 0, 0, 0);
  }
  #pragma unroll
  for (int oi = 0; oi < 2; ++oi)
    #pragma unroll
    for (int ni = 0; ni < 2; ++ni) {
      int o4 = ob + oi * 16 + g * 4;
      int n = nb + ni * 16 + l15;
      f32x4 b4 = *(const f32x4*)(bias + o4);
      f32x4 r = acc[oi][ni] + b4;
      *(f32x4*)(reft + ((size_t)(b * 1024) + n) * 256 + o4) = r;
    }
}

// ---------------- K7: scatter refined tokens back to pixels ----------------
// Thread owns (wpix, ii-pair): 9 aff taps in registers, refn read as f32x4
// channel-quads (ds_read_b128), 36-word row pad (16B-aligned, banks spread).
__global__ __launch_bounds__(256) void k7_scatter(const float* __restrict__ reft,
                                                  const float* __restrict__ aff2,
                                                  float* __restrict__ out) {
  __shared__ float refn[102][36];   // [dy*34+xx][c], c contiguous
  __shared__ float affl[4752];
  int t = threadIdx.x;
  int cg = blockIdx.x;  // 0..7 (32 channels each)
  int y = blockIdx.y;   // 0..31
  int b = blockIdx.z;
  int c0 = cg * 32;

  for (int i = t; i < 102 * 32; i += 256) {
    int c = i & 31;
    int row = i >> 5;               // dy*34 + xx
    int dy = row / 34, xx = row - dy * 34;
    int ny = y + dy - 1, nx = xx - 1;
    float v = 0.f;
    if (ny >= 0 && ny < 32 && nx >= 0 && nx < 32)
      v = reft[((size_t)(b * 1024) + ny * 32 + nx) * 256 + c0 + c];
    refn[row][c] = v;
  }
  int abase = (b * 32 + y) * 4752;
  for (int i = t; i < 4752; i += 256) affl[i] = aff2[abase + i];
  __syncthreads();

  int wpix = t & 127, iig = t >> 7;   // iig 0..1
  int xw = wpix >> 2, j = wpix & 3;
  size_t obase = (size_t)b * 4194304 + (size_t)c0 * 16384;
  #pragma unroll
  for (int ih = 0; ih < 2; ++ih) {
    int ii = iig * 2 + ih;
    int p = ii * 4 + j;
    float a[9];
    #pragma unroll
    for (int k = 0; k < 9; ++k) a[k] = affl[(p * 9 + k) * 33 + xw];
    size_t orow = obase + (size_t)(4 * y + ii) * 128 + wpix;
    #pragma unroll
    for (int c4 = 0; c4 < 8; ++c4) {
      f32x4 acc = {0.f, 0.f, 0.f, 0.f};
      #pragma unroll
      for (int k = 0; k < 9; ++k) {
        int dy = k / 3, kx = k % 3;
        f32x4 rv = *(const f32x4*)&refn[dy * 34 + xw + kx][c4 * 4];
        acc += a[k] * rv;
      }
      #pragma unroll
      for (int q = 0; q < 4; ++q)
        out[orow + (size_t)(c4 * 4 + q) * 16384] = acc[q];
    }
  }
}

extern "C" void kernel_launch(void* const* d_in, const int* in_sizes, int n_in,
                              void* d_out, int out_size, void* d_ws, size_t ws_size,
                              hipStream_t stream) {
  const float* x = (const float*)d_in[0];
  const float* qkvw = (const float*)d_in[1];
  const float* projw = (const float*)d_in[2];
  const float* projb = (const float*)d_in[3];
  float* out = (float*)d_out;
  char* ws = (char*)d_ws;

  unsigned short* wfbf   = (unsigned short*)(ws + 0);          // 4 MiB
  float* aff2            = (float*)(ws + 4194304);             // 4.87 MB
  unsigned short* agg    = (unsigned short*)(ws + 9060352);    // 37.7 MB
  float* asum_w          = (float*)(ws + 46809088);            // 288 KiB
  unsigned short* wf2bf  = (unsigned short*)(ws + 47104000);   // 4 MiB
  unsigned short* qt     = (unsigned short*)(ws + 51298304);   // 4 MiB
  unsigned short* kt     = (unsigned short*)(ws + 55492608);   // 4 MiB
  unsigned short* vt     = (unsigned short*)(ws + 59686912);   // 4 MiB
  unsigned short* refpre = (unsigned short*)(ws + 63881216);   // 4 MiB
  float* reft            = (float*)(ws + 68075520);            // 8 MiB
  unsigned short* wqkvbf = (unsigned short*)(ws + 76464128);
  unsigned short* wprojbf= (unsigned short*)(ws + 76857344);

  k0_wconv<<<768, 256, 0, stream>>>(qkvw, projw, wqkvbf, wprojbf);
  k1_pool<<<8192, 256, 0, stream>>>(x, wfbf);
  k2_winaff<<<2048, 256, 0, stream>>>(x, wfbf, aff2, agg, asum_w);
  k3_gather<<<8192, 256, 0, stream>>>(agg, asum_w, wf2bf);
  k4_qkv<<<dim3(16, 12, 8), 256, 0, stream>>>(wqkvbf, wf2bf, qt, kt, vt);
  k5_attn<<<dim3(32, 8, 8), 256, 0, stream>>>(qt, kt, vt, refpre);
  k6_proj<<<dim3(16, 4, 8), 256, 0, stream>>>(wprojbf, refpre, projb, reft);
  k7_scatter<<<dim3(8, 32, 8), 256, 0, stream>>>(reft, aff2, out);
}

// Round 7
// 370.479 us; speedup vs baseline: 1.0566x; 1.0566x over previous
//
#include <hip/hip_runtime.h>

typedef short short8 __attribute__((ext_vector_type(8)));
typedef float f32x4 __attribute__((ext_vector_type(4)));
typedef unsigned int uint2v __attribute__((ext_vector_type(2)));

__device__ __forceinline__ unsigned short f2bf(float x) {
  union { float f; unsigned int u; } v; v.f = x;
  unsigned int r = (v.u + 0x7FFFu + ((v.u >> 16) & 1u)) >> 16;
  return (unsigned short)r;
}
__device__ __forceinline__ float bf2f(unsigned short u) {
  union { unsigned int u; float f; } v; v.u = ((unsigned int)u) << 16;
  return v.f;
}

// ---------------- K0: convert weights to bf16 ----------------
__global__ __launch_bounds__(256) void k0_wconv(const float* __restrict__ qkvw,
                                                const float* __restrict__ projw,
                                                unsigned short* __restrict__ wqkvbf,
                                                unsigned short* __restrict__ wprojbf) {
  int i = blockIdx.x * 256 + threadIdx.x;
  if (i < 768 * 256) wqkvbf[i] = f2bf(qkvw[i]);
  if (i < 256 * 256) wprojbf[i] = f2bf(projw[i]);
}

// ---------------- K1: 4x4 avg pool -> wfbf (b, pos, c) bf16 ----------------
__global__ __launch_bounds__(256) void k1_pool(const float* __restrict__ x,
                                               unsigned short* __restrict__ wfbf) {
  int t = threadIdx.x;
  int blk = blockIdx.x;
  int b = blk >> 10, pos = blk & 1023;
  int y = pos >> 5, xw = pos & 31;
  const float* xb = x + (size_t)b * 4194304;
  float acc = 0.f;
  #pragma unroll
  for (int p = 0; p < 16; ++p) {
    int h = 4 * y + (p >> 2), w = 4 * xw + (p & 3);
    acc += xb[(size_t)(h * 128 + w) * 256 + t];
  }
  wfbf[(size_t)blk * 256 + t] = f2bf(acc * 0.0625f);
}

// ---------------- K2: per-window affinity (MFMA) + aggregate from LDS stash ----------------
// x is read from HBM exactly ONCE: the bf16-packed pixel rows (cv) are stashed
// to wave-private LDS during the MFMA loop and the aggregate phase reads them
// back from LDS (the global re-read thrashed L1/L2 across 32 waves/CU).
__global__ __launch_bounds__(256) void k2_winaff(const float* __restrict__ x,
                                                 const unsigned short* __restrict__ wfbf,
                                                 float* __restrict__ aff2,
                                                 unsigned short* __restrict__ agg,
                                                 float* __restrict__ asum_w) {
  __shared__ float aff_lds[4][16][16];
  __shared__ unsigned short pixs_bf[4][16][264];  // [wave][pixel][channel], +8 pad
  int tid = threadIdx.x, wv = tid >> 6, lane = tid & 63;
  int l15 = lane & 15, g = lane >> 4;
  int u = blockIdx.x * 4 + wv;          // window id
  int b = u >> 10, pos = u & 1023;
  int y = pos >> 5, xw = pos & 31;
  const float* xb = x + (size_t)b * 4194304;

  int dyi = l15 / 3 - 1, dxi = (l15 % 3) - 1;
  bool valid_n = (l15 < 9) && ((unsigned)(y + dyi) < 32u) && ((unsigned)(xw + dxi) < 32u);
  int un = valid_n ? (b * 1024 + (y + dyi) * 32 + (xw + dxi)) : 0;
  const unsigned short* wrow = wfbf + (size_t)un * 256;

  int ph = 4 * y + (l15 >> 2), pw = 4 * xw + (l15 & 3);
  const float* prow = xb + (size_t)(ph * 128 + pw) * 256;

  const short8 zero8 = {0, 0, 0, 0, 0, 0, 0, 0};
  f32x4 S = {0.f, 0.f, 0.f, 0.f};
  #pragma unroll
  for (int cc = 0; cc < 256; cc += 32) {
    short8 af = *(const short8*)(wrow + cc + g * 8);
    af = valid_n ? af : zero8;
    f32x4 lo = *(const f32x4*)(prow + cc + g * 8);
    f32x4 hi = *(const f32x4*)(prow + cc + g * 8 + 4);
    union { unsigned int w[4]; f32x4 f; } L, H;
    L.f = lo; H.f = hi;
    union { unsigned int w[4]; short8 s; } cv;
    cv.w[0] = (L.w[1] & 0xFFFF0000u) | (L.w[0] >> 16);
    cv.w[1] = (L.w[3] & 0xFFFF0000u) | (L.w[2] >> 16);
    cv.w[2] = (H.w[1] & 0xFFFF0000u) | (H.w[0] >> 16);
    cv.w[3] = (H.w[3] & 0xFFFF0000u) | (H.w[2] >> 16);
    *(short8*)&pixs_bf[wv][l15][cc + g * 8] = cv.s;   // wave-private stash
    S = __builtin_amdgcn_mfma_f32_16x16x32_bf16(af, cv.s, S, 0, 0, 0);
  }

  const float scale = 0.0625f;
  float Lg[4], e4[4];
  float pmax = -1e30f;
  #pragma unroll
  for (int r = 0; r < 4; ++r) {
    Lg[r] = S[r] * scale;
    bool v = (g * 4 + r) < 9;
    pmax = v ? fmaxf(pmax, Lg[r]) : pmax;
  }
  pmax = fmaxf(pmax, __shfl_xor(pmax, 16));
  pmax = fmaxf(pmax, __shfl_xor(pmax, 32));
  float esum = 0.f;
  #pragma unroll
  for (int r = 0; r < 4; ++r) {
    bool v = (g * 4 + r) < 9;
    e4[r] = v ? __expf(Lg[r] - pmax) : 0.f;
    esum += e4[r];
  }
  esum += __shfl_xor(esum, 16);
  esum += __shfl_xor(esum, 32);
  float inv = 1.f / esum;
  int rowbase = (b * 32 + y) * 4752;
  #pragma unroll
  for (int r = 0; r < 4; ++r) {
    float a = e4[r] * inv;
    aff_lds[wv][g * 4 + r][l15] = a;
    float s = a;
    s += __shfl_xor(s, 1); s += __shfl_xor(s, 2);
    s += __shfl_xor(s, 4); s += __shfl_xor(s, 8);
    if ((g * 4 + r) < 9) {
      aff2[rowbase + (l15 * 9 + g * 4 + r) * 33 + xw] = a;
      if (l15 == 0) asum_w[u * 9 + g * 4 + r] = s;
    }
  }

  // aggregate from the LDS stash (same wave wrote it; no barrier needed)
  f32x4 acc[9] = {};
  #pragma unroll
  for (int p = 0; p < 16; ++p) {
    unsigned long long pv = *(const unsigned long long*)&pixs_bf[wv][p][4 * lane];
    unsigned int w0 = (unsigned int)pv, w1 = (unsigned int)(pv >> 32);
    union { unsigned int u; float f; } t0, t1, t2, t3;
    t0.u = w0 << 16; t1.u = w0 & 0xFFFF0000u;
    t2.u = w1 << 16; t3.u = w1 & 0xFFFF0000u;
    f32x4 pf = {t0.f, t1.f, t2.f, t3.f};
    #pragma unroll
    for (int k = 0; k < 9; ++k) {
      float ab = aff_lds[wv][k][p];
      acc[k] += ab * pf;
    }
  }
  #pragma unroll
  for (int k = 0; k < 9; ++k) {
    uint2v st;
    st.x = ((unsigned int)f2bf(acc[k][1]) << 16) | f2bf(acc[k][0]);
    st.y = ((unsigned int)f2bf(acc[k][3]) << 16) | f2bf(acc[k][2]);
    *(uint2v*)(agg + ((size_t)u * 9 + k) * 256 + 4 * lane) = st;
  }
}

// ---------------- K3: gather fold + normalize -> wf2 bf16 (b, pos, c) ----------------
__global__ __launch_bounds__(256) void k3_gather(const unsigned short* __restrict__ agg,
                                                 const float* __restrict__ asum_w,
                                                 unsigned short* __restrict__ wf2bf) {
  int t = threadIdx.x;
  int blk = blockIdx.x;
  int b = blk >> 10, pos = blk & 1023;
  int y = pos >> 5, xw = pos & 31;
  float acc = 0.f, den = 0.f;
  #pragma unroll
  for (int i = 0; i < 9; ++i) {
    int dy = i / 3 - 1, dx = i % 3 - 1;
    int sy = y - dy, sx = xw - dx;
    if (sy < 0 || sy >= 32 || sx < 0 || sx >= 32) continue;
    size_t un = (size_t)(b * 1024) + sy * 32 + sx;
    acc += bf2f(agg[(un * 9 + i) * 256 + t]);
    den += asum_w[un * 9 + i];
  }
  wf2bf[(size_t)blk * 256 + t] = f2bf(acc / (den + 1e-12f));
}

// ---------------- K4: qkv GEMM (768x256 @ 256x1024 per b), MFMA bf16 ----------------
__global__ __launch_bounds__(256) void k4_qkv(const unsigned short* __restrict__ wbf,
                                              const unsigned short* __restrict__ xbf,
                                              unsigned short* __restrict__ qt,
                                              unsigned short* __restrict__ kt,
                                              unsigned short* __restrict__ vt) {
  int tid = threadIdx.x, lane = tid & 63, wv = tid >> 6;
  int l15 = lane & 15, g = lane >> 4;
  int nb = blockIdx.x * 64 + (wv & 1) * 32;
  int ob = blockIdx.y * 64 + (wv >> 1) * 32;
  int b = blockIdx.z;
  const unsigned short* X = xbf + (size_t)b * 262144;
  f32x4 acc[2][2] = {};
  for (int cc = 0; cc < 256; cc += 32) {
    short8 af[2], bfr[2];
    #pragma unroll
    for (int oi = 0; oi < 2; ++oi)
      af[oi] = *(const short8*)(wbf + (size_t)(ob + oi * 16 + l15) * 256 + cc + g * 8);
    #pragma unroll
    for (int ni = 0; ni < 2; ++ni)
      bfr[ni] = *(const short8*)(X + (size_t)(nb + ni * 16 + l15) * 256 + cc + g * 8);
    #pragma unroll
    for (int oi = 0; oi < 2; ++oi)
      #pragma unroll
      for (int ni = 0; ni < 2; ++ni)
        acc[oi][ni] = __builtin_amdgcn_mfma_f32_16x16x32_bf16(af[oi], bfr[ni], acc[oi][ni], 0, 0, 0);
  }
  #pragma unroll
  for (int oi = 0; oi < 2; ++oi)
    #pragma unroll
    for (int ni = 0; ni < 2; ++ni)
      #pragma unroll
      for (int r = 0; r < 4; ++r) {
        int o = ob + oi * 16 + g * 4 + r;
        int n = nb + ni * 16 + l15;
        unsigned short bv = f2bf(acc[oi][ni][r]);
        int head = o / 96;
        int rr = o - head * 96;
        size_t bh = (size_t)(b * 8 + head);
        if (rr < 32) qt[(bh * 1024 + n) * 32 + rr] = bv;
        else if (rr < 64) kt[(bh * 1024 + n) * 32 + (rr - 32)] = bv;
        else vt[(bh * 32 + (rr - 64)) * 1024 + n] = bv;
      }
}

// ---------------- K5: attention per (b,h,mtile), softmax over keys ----------------
__global__ __launch_bounds__(256) void k5_attn(const unsigned short* __restrict__ qt,
                                               const unsigned short* __restrict__ kt,
                                               const unsigned short* __restrict__ vt,
                                               unsigned short* __restrict__ refpre) {
  __shared__ short P_lds[4][32][40];
  __shared__ float out_lds[4][32][33];
  __shared__ float den_lds[4][32];
  int tid = threadIdx.x, lane = tid & 63, wv = tid >> 6;
  int l15 = lane & 15, g = lane >> 4;
  int mt = blockIdx.x, h = blockIdx.y, b = blockIdx.z;
  const unsigned short* qtb = qt + ((size_t)(b * 8 + h) * 1024) * 32;
  const unsigned short* ktb = kt + ((size_t)(b * 8 + h) * 1024) * 32;
  const unsigned short* vtb = vt + ((size_t)(b * 8 + h) * 32) * 1024;

  short8 qf[2];
  #pragma unroll
  for (int mi = 0; mi < 2; ++mi) {
    int m = mt * 32 + mi * 16 + l15;
    qf[mi] = *(const short8*)(qtb + (size_t)m * 32 + g * 8);
  }
  f32x4 oacc[2][2] = {};
  float dsum0 = 0.f, dsum1 = 0.f;
  const float hs = 0.17677669529663687f;

  for (int c8 = 0; c8 < 8; ++c8) {
    int nchunk = wv * 256 + c8 * 32;
    f32x4 sf[2][2];
    #pragma unroll
    for (int nt = 0; nt < 2; ++nt) {
      int n = nchunk + nt * 16 + l15;
      short8 kf = *(const short8*)(ktb + (size_t)n * 32 + g * 8);
      #pragma unroll
      for (int mi = 0; mi < 2; ++mi) {
        f32x4 z = {0.f, 0.f, 0.f, 0.f};
        sf[nt][mi] = __builtin_amdgcn_mfma_f32_16x16x32_bf16(kf, qf[mi], z, 0, 0, 0);
      }
    }
    #pragma unroll
    for (int nt = 0; nt < 2; ++nt)
      #pragma unroll
      for (int mi = 0; mi < 2; ++mi) {
        float p0 = __expf(hs * sf[nt][mi][0]);
        float p1 = __expf(hs * sf[nt][mi][1]);
        float p2 = __expf(hs * sf[nt][mi][2]);
        float p3 = __expf(hs * sf[nt][mi][3]);
        float ds = (p0 + p1) + (p2 + p3);
        if (mi == 0) dsum0 += ds; else dsum1 += ds;
        unsigned int w01 = ((unsigned int)f2bf(p1) << 16) | f2bf(p0);
        unsigned int w23 = ((unsigned int)f2bf(p3) << 16) | f2bf(p2);
        int ml = mi * 16 + l15;
        int nn = nt * 16 + g * 4;
        *(unsigned int*)&P_lds[wv][ml][nn] = w01;
        *(unsigned int*)&P_lds[wv][ml][nn + 2] = w23;
      }
    #pragma unroll
    for (int dh = 0; dh < 2; ++dh) {
      short8 vf = *(const short8*)(vtb + (size_t)(dh * 16 + l15) * 1024 + nchunk + g * 8);
      #pragma unroll
      for (int mi = 0; mi < 2; ++mi) {
        short8 pf = *(const short8*)&P_lds[wv][mi * 16 + l15][g * 8];
        oacc[dh][mi] = __builtin_amdgcn_mfma_f32_16x16x32_bf16(vf, pf, oacc[dh][mi], 0, 0, 0);
      }
    }
  }

  dsum0 += __shfl_xor(dsum0, 16); dsum0 += __shfl_xor(dsum0, 32);
  dsum1 += __shfl_xor(dsum1, 16); dsum1 += __shfl_xor(dsum1, 32);
  if (lane < 16) { den_lds[wv][lane] = dsum0; den_lds[wv][16 + lane] = dsum1; }
  #pragma unroll
  for (int dh = 0; dh < 2; ++dh)
    #pragma unroll
    for (int mi = 0; mi < 2; ++mi)
      #pragma unroll
      for (int r = 0; r < 4; ++r)
        out_lds[wv][dh * 16 + g * 4 + r][mi * 16 + l15] = oacc[dh][mi][r];
  __syncthreads();

  #pragma unroll
  for (int kk = 0; kk < 4; ++kk) {
    int idx = kk * 256 + tid;
    int d = idx & 31, m = idx >> 5;
    float v = out_lds[0][d][m] + out_lds[1][d][m] + out_lds[2][d][m] + out_lds[3][d][m];
    float den = den_lds[0][m] + den_lds[1][m] + den_lds[2][m] + den_lds[3][m];
    float res = v / den;
    int n = mt * 32 + m;
    refpre[((size_t)(b * 1024) + n) * 256 + h * 32 + d] = f2bf(res);
  }
}

// ---------------- K6: proj GEMM + bias -> reftbf (b, pos, c) bf16 ----------------
__global__ __launch_bounds__(256) void k6_proj(const unsigned short* __restrict__ wbf,
                                               const unsigned short* __restrict__ xbf,
                                               const float* __restrict__ bias,
                                               unsigned short* __restrict__ reftbf) {
  int tid = threadIdx.x, lane = tid & 63, wv = tid >> 6;
  int l15 = lane & 15, g = lane >> 4;
  int nb = blockIdx.x * 64 + (wv & 1) * 32;
  int ob = blockIdx.y * 64 + (wv >> 1) * 32;
  int b = blockIdx.z;
  const unsigned short* X = xbf + (size_t)b * 262144;
  f32x4 acc[2][2] = {};
  for (int cc = 0; cc < 256; cc += 32) {
    short8 af[2], bfr[2];
    #pragma unroll
    for (int oi = 0; oi < 2; ++oi)
      af[oi] = *(const short8*)(wbf + (size_t)(ob + oi * 16 + l15) * 256 + cc + g * 8);
    #pragma unroll
    for (int ni = 0; ni < 2; ++ni)
      bfr[ni] = *(const short8*)(X + (size_t)(nb + ni * 16 + l15) * 256 + cc + g * 8);
    #pragma unroll
    for (int oi = 0; oi < 2; ++oi)
      #pragma unroll
      for (int ni = 0; ni < 2; ++ni)
        acc[oi][ni] = __builtin_amdgcn_mfma_f32_16x16x32_bf16(af[oi], bfr[ni], acc[oi][ni], 0, 0, 0);
  }
  #pragma unroll
  for (int oi = 0; oi < 2; ++oi)
    #pragma unroll
    for (int ni = 0; ni < 2; ++ni) {
      int o4 = ob + oi * 16 + g * 4;
      int n = nb + ni * 16 + l15;
      f32x4 b4 = *(const f32x4*)(bias + o4);
      f32x4 r = acc[oi][ni] + b4;
      uint2v st;
      st.x = ((unsigned int)f2bf(r[1]) << 16) | f2bf(r[0]);
      st.y = ((unsigned int)f2bf(r[3]) << 16) | f2bf(r[2]);
      *(uint2v*)(reftbf + ((size_t)(b * 1024) + n) * 256 + o4) = st;
    }
}

// ---------------- K7: scatter refined tokens back to pixels ----------------
__global__ __launch_bounds__(256) void k7_scatter(const unsigned short* __restrict__ reftbf,
                                                  const float* __restrict__ aff2,
                                                  float* __restrict__ out) {
  __shared__ float refn[102][36];   // [dy*34+xx][c], c contiguous
  __shared__ float affl[4752];
  int t = threadIdx.x;
  int cg = blockIdx.x;  // 0..7 (32 channels each)
  int y = blockIdx.y;   // 0..31
  int b = blockIdx.z;
  int c0 = cg * 32;

  for (int i = t; i < 102 * 16; i += 256) {
    int c2 = i & 15;                // 2-channel group
    int row = i >> 4;               // dy*34 + xx
    int dy = row / 34, xx = row - dy * 34;
    int ny = y + dy - 1, nx = xx - 1;
    float v0 = 0.f, v1 = 0.f;
    if (ny >= 0 && ny < 32 && nx >= 0 && nx < 32) {
      unsigned int pv = *(const unsigned int*)(reftbf +
          ((size_t)(b * 1024) + ny * 32 + nx) * 256 + c0 + 2 * c2);
      union { unsigned int u; float f; } a0, a1;
      a0.u = pv << 16; a1.u = pv & 0xFFFF0000u;
      v0 = a0.f; v1 = a1.f;
    }
    refn[row][2 * c2] = v0;
    refn[row][2 * c2 + 1] = v1;
  }
  int abase = (b * 32 + y) * 4752;
  for (int i = t; i < 4752; i += 256) affl[i] = aff2[abase + i];
  __syncthreads();

  int wpix = t & 127, iig = t >> 7;   // iig 0..1
  int xw = wpix >> 2, j = wpix & 3;
  size_t obase = (size_t)b * 4194304 + (size_t)c0 * 16384;
  #pragma unroll
  for (int ih = 0; ih < 2; ++ih) {
    int ii = iig * 2 + ih;
    int p = ii * 4 + j;
    float a[9];
    #pragma unroll
    for (int k = 0; k < 9; ++k) a[k] = affl[(p * 9 + k) * 33 + xw];
    size_t orow = obase + (size_t)(4 * y + ii) * 128 + wpix;
    #pragma unroll
    for (int c4 = 0; c4 < 8; ++c4) {
      f32x4 acc = {0.f, 0.f, 0.f, 0.f};
      #pragma unroll
      for (int k = 0; k < 9; ++k) {
        int dy = k / 3, kx = k % 3;
        f32x4 rv = *(const f32x4*)&refn[dy * 34 + xw + kx][c4 * 4];
        acc += a[k] * rv;
      }
      #pragma unroll
      for (int q = 0; q < 4; ++q)
        out[orow + (size_t)(c4 * 4 + q) * 16384] = acc[q];
    }
  }
}

extern "C" void kernel_launch(void* const* d_in, const int* in_sizes, int n_in,
                              void* d_out, int out_size, void* d_ws, size_t ws_size,
                              hipStream_t stream) {
  const float* x = (const float*)d_in[0];
  const float* qkvw = (const float*)d_in[1];
  const float* projw = (const float*)d_in[2];
  const float* projb = (const float*)d_in[3];
  float* out = (float*)d_out;
  char* ws = (char*)d_ws;

  unsigned short* wfbf   = (unsigned short*)(ws + 0);          // 4 MiB
  float* aff2            = (float*)(ws + 4194304);             // 4.87 MB
  unsigned short* agg    = (unsigned short*)(ws + 9060352);    // 37.7 MB
  float* asum_w          = (float*)(ws + 46809088);            // 288 KiB
  unsigned short* wf2bf  = (unsigned short*)(ws + 47104000);   // 4 MiB
  unsigned short* qt     = (unsigned short*)(ws + 51298304);   // 4 MiB
  unsigned short* kt     = (unsigned short*)(ws + 55492608);   // 4 MiB
  unsigned short* vt     = (unsigned short*)(ws + 59686912);   // 4 MiB
  unsigned short* refpre = (unsigned short*)(ws + 63881216);   // 4 MiB
  unsigned short* reftbf = (unsigned short*)(ws + 68075520);   // 4.2 MB
  unsigned short* wqkvbf = (unsigned short*)(ws + 76464128);
  unsigned short* wprojbf= (unsigned short*)(ws + 76857344);

  k0_wconv<<<768, 256, 0, stream>>>(qkvw, projw, wqkvbf, wprojbf);
  k1_pool<<<8192, 256, 0, stream>>>(x, wfbf);
  k2_winaff<<<2048, 256, 0, stream>>>(x, wfbf, aff2, agg, asum_w);
  k3_gather<<<8192, 256, 0, stream>>>(agg, asum_w, wf2bf);
  k4_qkv<<<dim3(16, 12, 8), 256, 0, stream>>>(wqkvbf, wf2bf, qt, kt, vt);
  k5_attn<<<dim3(32, 8, 8), 256, 0, stream>>>(qt, kt, vt, refpre);
  k6_proj<<<dim3(16, 4, 8), 256, 0, stream>>>(wprojbf, refpre, projb, reftbf);
  k7_scatter<<<dim3(8, 32, 8), 256, 0, stream>>>(reftbf, aff2, out);
}